// Round 1
// baseline (1321.902 us; speedup 1.0000x reference)
//
#include <hip/hip_runtime.h>

typedef unsigned short u16;
typedef __attribute__((ext_vector_type(8))) short bf16x8;
typedef __attribute__((ext_vector_type(4))) float f32x4;

#define NTOK 32768
#define CC 512
#define HH 8
#define LL 64
#define NBLK 512

__device__ __forceinline__ u16 f2bf(float f) {
    unsigned int u = __float_as_uint(f);
    unsigned int r = u + 0x7fffu + ((u >> 16) & 1u);
    return (u16)(r >> 16);
}
__device__ __forceinline__ float bf2f(u16 h) {
    return __uint_as_float(((unsigned int)h) << 16);
}
__device__ __forceinline__ bf16x8 bc8(uint4 v) {
    return __builtin_bit_cast(bf16x8, v);
}

// ---------------- kernel 0: x fp32 -> bf16 ----------------
__global__ __launch_bounds__(256) void convert_x_kernel(const float* __restrict__ x,
                                                        u16* __restrict__ xbf) {
    size_t i = ((size_t)blockIdx.x * 256 + threadIdx.x) * 8;
    const float4* p = (const float4*)(x + i);
    float4 a = p[0], b = p[1];
    uint4 o;
    o.x = (unsigned)f2bf(a.x) | ((unsigned)f2bf(a.y) << 16);
    o.y = (unsigned)f2bf(a.z) | ((unsigned)f2bf(a.w) << 16);
    o.z = (unsigned)f2bf(b.x) | ((unsigned)f2bf(b.y) << 16);
    o.w = (unsigned)f2bf(b.z) | ((unsigned)f2bf(b.w) << 16);
    *(uint4*)(xbf + i) = o;
}

// ---------------- kernel 1: transpose fp32 [K][Nn] -> bf16 [Nn][K] ----------------
__global__ __launch_bounds__(256) void transpose_bf16_kernel(const float* __restrict__ in,
                                                             u16* __restrict__ out,
                                                             int K, int Nn) {
    __shared__ float tile[32][33];
    int n0 = blockIdx.x * 32, k0 = blockIdx.y * 32;
    int tx = threadIdx.x & 31, ty = threadIdx.x >> 5;  // ty 0..7
#pragma unroll
    for (int i = 0; i < 4; ++i)
        tile[ty + i * 8][tx] = in[(size_t)(k0 + ty + i * 8) * Nn + n0 + tx];
    __syncthreads();
#pragma unroll
    for (int i = 0; i < 4; ++i)
        out[(size_t)(n0 + ty + i * 8) * K + k0 + tx] = f2bf(tile[tx][ty + i * 8]);
}

// ---------------- kernel 2: per-(nb,q,k) sbias + gate MLP ----------------
__global__ __launch_bounds__(256) void gate_sbias_kernel(const int* __restrict__ mask,
                                                         const float* __restrict__ edge,
                                                         const float* __restrict__ w1,
                                                         const float* __restrict__ b1,
                                                         const float* __restrict__ w2,
                                                         const float* __restrict__ b2,
                                                         u16* __restrict__ gate,
                                                         float* __restrict__ sbias) {
    __shared__ float w1s[64], b1s[16], w2s[128], b2s[8];
    __shared__ int nds[64];
    int t = threadIdx.x;
    int nb = blockIdx.x;
    if (t < 64) w1s[t] = w1[t];
    if (t < 16) b1s[t] = b1[t];
    if (t < 128) w2s[t] = w2[t];
    if (t < 8) b2s[t] = b2[t];
    if (t < 64) {
        int s = 0;
        const int* mr = mask + (size_t)(nb * 64 + t) * 64;
#pragma unroll 8
        for (int k = 0; k < 64; ++k) s += mr[k];
        nds[t] = (s < 1) ? 1 : 0;
    }
    __syncthreads();
#pragma unroll 1
    for (int it = 0; it < 16; ++it) {
        int p = it * 256 + t;
        int q = p >> 6, k = p & 63;
        int mv = mask[(size_t)(nb * 64 + q) * 64 + k];
        float e0, e1, e2, e3;
        if (q == k) {
            mv = max(mv, nds[q]);
            e0 = e1 = e2 = 0.f;
            e3 = 1.f;
        } else {
            const float* ep = edge + ((size_t)(nb * 64 + q) * 64 + k) * 4;
            e0 = ep[0]; e1 = ep[1]; e2 = ep[2]; e3 = ep[3];
        }
        sbias[(size_t)(nb * 64 + q) * 64 + k] = mv ? e3 : -1e30f;
        float g[8];
#pragma unroll
        for (int hh = 0; hh < 8; ++hh) g[hh] = b2s[hh];
#pragma unroll
        for (int j = 0; j < 16; ++j) {
            float hpre = e0 * w1s[j] + e1 * w1s[16 + j] + e2 * w1s[32 + j] + e3 * w1s[48 + j] + b1s[j];
            float hg = 0.5f * hpre * (1.f + erff(hpre * 0.70710678f));
#pragma unroll
            for (int hh = 0; hh < 8; ++hh) g[hh] += hg * w2s[j * 8 + hh];
        }
#pragma unroll
        for (int hh = 0; hh < 8; ++hh)
            gate[(((size_t)nb * 8 + hh) * 64 + q) * 64 + k] = f2bf(mv ? g[hh] : 0.f);
    }
}

// ---------------- kernel 3: fused per-(b,nb,h) attention ----------------
__global__ __launch_bounds__(256) void attn_kernel(const u16* __restrict__ xbf,
                                                   const u16* __restrict__ wqkvT,
                                                   const float* __restrict__ b_qkv,
                                                   const float* __restrict__ w_blk,
                                                   const float* __restrict__ b_blk,
                                                   const float* __restrict__ sbias,
                                                   const u16* __restrict__ gate,
                                                   u16* __restrict__ xmid) {
    __shared__ u16 Qs[64 * 72], Ks[64 * 72], VT[64 * 72], Ps[64 * 72];
    __shared__ float gl[64], vbl[64], wbc[512];
    int tid = threadIdx.x;
    int bid = blockIdx.x;
    int h = bid & 7, nb = (bid >> 3) & 511, b = bid >> 12;
    int lane = tid & 63, l15 = lane & 15, quad = lane >> 4, wave = tid >> 6;
    int m0 = wave * 16;
    size_t blockrow = (size_t)(b * NTOK + nb * 64);

    // stage w_blk column h
    for (int i = tid; i < 512; i += 256) wbc[i] = w_blk[i * 8 + h];
    __syncthreads();

    // ---- g_block = sigmoid(x_blk . w_blk[:,h] + b_blk[h]) ----
    if (tid < 64) {
        const uint4* xr = (const uint4*)(xbf + (blockrow + tid) * CC);
        float acc = 0.f;
#pragma unroll 4
        for (int c = 0; c < 64; ++c) {
            uint4 v = xr[c];
            acc += bf2f((u16)(v.x & 0xffff)) * wbc[c * 8 + 0];
            acc += bf2f((u16)(v.x >> 16)) * wbc[c * 8 + 1];
            acc += bf2f((u16)(v.y & 0xffff)) * wbc[c * 8 + 2];
            acc += bf2f((u16)(v.y >> 16)) * wbc[c * 8 + 3];
            acc += bf2f((u16)(v.z & 0xffff)) * wbc[c * 8 + 4];
            acc += bf2f((u16)(v.z >> 16)) * wbc[c * 8 + 5];
            acc += bf2f((u16)(v.w & 0xffff)) * wbc[c * 8 + 6];
            acc += bf2f((u16)(v.w >> 16)) * wbc[c * 8 + 7];
        }
        gl[tid] = 1.f / (1.f + __expf(-(acc + b_blk[h])));
    }

    // ---- QKV GEMM: X(64x512) @ Wh(512x192), wave w owns 16 rows x 192 cols ----
    f32x4 acc[12];
#pragma unroll
    for (int t = 0; t < 12; ++t) acc[t] = (f32x4){0.f, 0.f, 0.f, 0.f};
    const uint4* pA = (const uint4*)(xbf + (blockrow + m0 + l15) * CC);
    int boff[12];
#pragma unroll
    for (int t = 0; t < 12; ++t) {
        int nglob = (t >> 2) * CC + h * 64 + (t & 3) * 16 + l15;
        boff[t] = nglob * CC;
    }
#pragma unroll 2
    for (int kk = 0; kk < 16; ++kk) {
        bf16x8 a = bc8(pA[kk * 4 + quad]);
#pragma unroll
        for (int t = 0; t < 12; ++t) {
            bf16x8 bb = bc8(*(const uint4*)(wqkvT + boff[t] + kk * 32 + quad * 8));
            acc[t] = __builtin_amdgcn_mfma_f32_16x16x32_bf16(a, bb, acc[t], 0, 0, 0);
        }
    }
#pragma unroll
    for (int t = 0; t < 12; ++t) {
        int sec = t >> 2, nl = (t & 3) * 16 + l15;
        float bias = b_qkv[sec * CC + h * 64 + nl];
#pragma unroll
        for (int r = 0; r < 4; ++r) {
            float v = acc[t][r] + bias;
            int row = m0 + quad * 4 + r;
            if (sec == 0) Qs[row * 72 + nl] = f2bf(v);
            else if (sec == 1) Ks[row * 72 + nl] = f2bf(v);
            else VT[nl * 72 + row] = f2bf(v);  // V transposed: VT[d][key]
        }
    }
    __syncthreads();

    // ---- v_block[d] = column mean of V (includes b_qkv) ----
    if (tid < 64) {
        float s = 0.f;
#pragma unroll 8
        for (int k = 0; k < 64; ++k) s += bf2f(VT[tid * 72 + k]);
        vbl[tid] = s * 0.015625f;
    }

    // ---- scores = Q @ K^T * 0.125 + sbias; softmax; +gate; -> P(bf16 LDS) ----
    f32x4 sc[4];
#pragma unroll
    for (int t = 0; t < 4; ++t) sc[t] = (f32x4){0.f, 0.f, 0.f, 0.f};
#pragma unroll
    for (int kk = 0; kk < 2; ++kk) {
        bf16x8 a = *(const bf16x8*)&Qs[(m0 + l15) * 72 + kk * 32 + quad * 8];
#pragma unroll
        for (int t = 0; t < 4; ++t) {
            bf16x8 bb = *(const bf16x8*)&Ks[(t * 16 + l15) * 72 + kk * 32 + quad * 8];
            sc[t] = __builtin_amdgcn_mfma_f32_16x16x32_bf16(a, bb, sc[t], 0, 0, 0);
        }
    }
    {
        const float* sbp = sbias + (size_t)nb * 64 * 64;
#pragma unroll
        for (int r = 0; r < 4; ++r) {
            int q = m0 + quad * 4 + r;
            float mx = -3e38f;
#pragma unroll
            for (int t = 0; t < 4; ++t) {
                float v = sc[t][r] * 0.125f + sbp[q * 64 + t * 16 + l15];
                sc[t][r] = v;
                mx = fmaxf(mx, v);
            }
            mx = fmaxf(mx, __shfl_xor(mx, 1));
            mx = fmaxf(mx, __shfl_xor(mx, 2));
            mx = fmaxf(mx, __shfl_xor(mx, 4));
            mx = fmaxf(mx, __shfl_xor(mx, 8));
            float sum = 0.f;
#pragma unroll
            for (int t = 0; t < 4; ++t) {
                float p = __expf(sc[t][r] - mx);
                sc[t][r] = p;
                sum += p;
            }
            sum += __shfl_xor(sum, 1);
            sum += __shfl_xor(sum, 2);
            sum += __shfl_xor(sum, 4);
            sum += __shfl_xor(sum, 8);
            float inv = 1.f / sum;
            const u16* gp = gate + (((size_t)nb * 8 + h) * 64 + q) * 64;
#pragma unroll
            for (int t = 0; t < 4; ++t) {
                float comb = sc[t][r] * inv + bf2f(gp[t * 16 + l15]);
                Ps[q * 72 + t * 16 + l15] = f2bf(comb);
            }
        }
    }
    __syncthreads();

    // ---- x_mid = P @ V  (+ g_block * v_block) ----
    f32x4 o[4];
#pragma unroll
    for (int t = 0; t < 4; ++t) o[t] = (f32x4){0.f, 0.f, 0.f, 0.f};
#pragma unroll
    for (int kk = 0; kk < 2; ++kk) {
        bf16x8 a = *(const bf16x8*)&Ps[(m0 + l15) * 72 + kk * 32 + quad * 8];
#pragma unroll
        for (int t = 0; t < 4; ++t) {
            bf16x8 bb = *(const bf16x8*)&VT[(t * 16 + l15) * 72 + kk * 32 + quad * 8];
            o[t] = __builtin_amdgcn_mfma_f32_16x16x32_bf16(a, bb, o[t], 0, 0, 0);
        }
    }
#pragma unroll
    for (int t = 0; t < 4; ++t) {
#pragma unroll
        for (int r = 0; r < 4; ++r) {
            int q = m0 + quad * 4 + r, d = t * 16 + l15;
            float v = o[t][r] + gl[q] * vbl[d];
            xmid[(blockrow + q) * CC + h * 64 + d] = f2bf(v);
        }
    }
}

// ---------------- kernel 4: out = x_mid @ w_proj + b_proj ----------------
__global__ __launch_bounds__(256) void outproj_kernel(const u16* __restrict__ xmid,
                                                      const u16* __restrict__ wprojT,
                                                      const float* __restrict__ b_proj,
                                                      float* __restrict__ out) {
    int tid = threadIdx.x, bid = blockIdx.x;
    int mb = bid >> 2, nbk = bid & 3;
    int lane = tid & 63, l15 = lane & 15, quad = lane >> 4, wave = tid >> 6;
    int mw = mb * 128 + (wave >> 1) * 64;
    int nw = nbk * 128 + (wave & 1) * 64;
    f32x4 acc[4][4];
#pragma unroll
    for (int mt = 0; mt < 4; ++mt)
#pragma unroll
        for (int nt = 0; nt < 4; ++nt) acc[mt][nt] = (f32x4){0.f, 0.f, 0.f, 0.f};
    const u16* pa[4];
    const u16* pb[4];
#pragma unroll
    for (int mt = 0; mt < 4; ++mt) pa[mt] = xmid + (size_t)(mw + mt * 16 + l15) * CC;
#pragma unroll
    for (int nt = 0; nt < 4; ++nt) pb[nt] = wprojT + (size_t)(nw + nt * 16 + l15) * CC;
#pragma unroll 2
    for (int kk = 0; kk < 16; ++kk) {
        int ko = kk * 32 + quad * 8;
        bf16x8 a[4], bb[4];
#pragma unroll
        for (int mt = 0; mt < 4; ++mt) a[mt] = bc8(*(const uint4*)(pa[mt] + ko));
#pragma unroll
        for (int nt = 0; nt < 4; ++nt) bb[nt] = bc8(*(const uint4*)(pb[nt] + ko));
#pragma unroll
        for (int mt = 0; mt < 4; ++mt)
#pragma unroll
            for (int nt = 0; nt < 4; ++nt)
                acc[mt][nt] = __builtin_amdgcn_mfma_f32_16x16x32_bf16(a[mt], bb[nt], acc[mt][nt], 0, 0, 0);
    }
#pragma unroll
    for (int mt = 0; mt < 4; ++mt)
#pragma unroll
        for (int nt = 0; nt < 4; ++nt) {
            int col = nw + nt * 16 + l15;
            float bp = b_proj[col];
#pragma unroll
            for (int r = 0; r < 4; ++r) {
                int row = mw + mt * 16 + quad * 4 + r;
                out[(size_t)row * CC + col] = acc[mt][nt][r] + bp;
            }
        }
}

extern "C" void kernel_launch(void* const* d_in, const int* in_sizes, int n_in,
                              void* d_out, int out_size, void* d_ws, size_t ws_size,
                              hipStream_t stream) {
    const float* x = (const float*)d_in[0];
    const int* attn_mask = (const int*)d_in[1];
    const float* edge = (const float*)d_in[2];
    const float* w_qkv = (const float*)d_in[3];
    const float* b_qkv = (const float*)d_in[4];
    const float* w_proj = (const float*)d_in[5];
    const float* b_proj = (const float*)d_in[6];
    const float* w_eg1 = (const float*)d_in[7];
    const float* b_eg1 = (const float*)d_in[8];
    const float* w_eg2 = (const float*)d_in[9];
    const float* b_eg2 = (const float*)d_in[10];
    const float* w_blk = (const float*)d_in[11];
    const float* b_blk = (const float*)d_in[12];
    float* out = (float*)d_out;

    char* ws = (char*)d_ws;
    u16* xbf = (u16*)ws;                           // 2*32768*512*2  = 67108864
    u16* xmid = (u16*)(ws + 67108864);             // 67108864
    u16* gate = (u16*)(ws + 134217728);            // 512*8*4096*2  = 33554432
    float* sbias = (float*)(ws + 167772160);       // 512*4096*4    = 8388608
    u16* wqkvT = (u16*)(ws + 176160768);           // 1536*512*2    = 1572864
    u16* wprojT = (u16*)(ws + 177733632);          // 512*512*2     = 524288

    convert_x_kernel<<<16384, 256, 0, stream>>>(x, xbf);
    transpose_bf16_kernel<<<dim3(48, 16), 256, 0, stream>>>(w_qkv, wqkvT, 512, 1536);
    transpose_bf16_kernel<<<dim3(16, 16), 256, 0, stream>>>(w_proj, wprojT, 512, 512);
    gate_sbias_kernel<<<512, 256, 0, stream>>>(attn_mask, edge, w_eg1, b_eg1, w_eg2, b_eg2,
                                               gate, sbias);
    attn_kernel<<<8192, 256, 0, stream>>>(xbf, wqkvT, b_qkv, w_blk, b_blk, sbias, gate, xmid);
    outproj_kernel<<<2048, 256, 0, stream>>>(xmid, wprojT, b_proj, out);
}

// Round 2
// 998.205 us; speedup vs baseline: 1.3243x; 1.3243x over previous
//
#include <hip/hip_runtime.h>

typedef unsigned short u16;
typedef __attribute__((ext_vector_type(8))) short bf16x8;
typedef __attribute__((ext_vector_type(4))) float f32x4;

#define NTOK 32768
#define CC 512
#define HH 8
#define LL 64
#define NBLK 512

__device__ __forceinline__ u16 f2bf(float f) {
    unsigned int u = __float_as_uint(f);
    unsigned int r = u + 0x7fffu + ((u >> 16) & 1u);
    return (u16)(r >> 16);
}
__device__ __forceinline__ float bf2f(u16 h) {
    return __uint_as_float(((unsigned int)h) << 16);
}
__device__ __forceinline__ bf16x8 bc8(uint4 v) {
    return __builtin_bit_cast(bf16x8, v);
}

// ---------------- kernel 0: x fp32 -> bf16 ----------------
__global__ __launch_bounds__(256) void convert_x_kernel(const float* __restrict__ x,
                                                        u16* __restrict__ xbf) {
    size_t i = ((size_t)blockIdx.x * 256 + threadIdx.x) * 8;
    const float4* p = (const float4*)(x + i);
    float4 a = p[0], b = p[1];
    uint4 o;
    o.x = (unsigned)f2bf(a.x) | ((unsigned)f2bf(a.y) << 16);
    o.y = (unsigned)f2bf(a.z) | ((unsigned)f2bf(a.w) << 16);
    o.z = (unsigned)f2bf(b.x) | ((unsigned)f2bf(b.y) << 16);
    o.w = (unsigned)f2bf(b.z) | ((unsigned)f2bf(b.w) << 16);
    *(uint4*)(xbf + i) = o;
}

// ---------------- kernel 1: transpose fp32 [K][Nn] -> bf16 [Nn][K] ----------------
__global__ __launch_bounds__(256) void transpose_bf16_kernel(const float* __restrict__ in,
                                                             u16* __restrict__ out,
                                                             int K, int Nn) {
    __shared__ float tile[32][33];
    int n0 = blockIdx.x * 32, k0 = blockIdx.y * 32;
    int tx = threadIdx.x & 31, ty = threadIdx.x >> 5;  // ty 0..7
#pragma unroll
    for (int i = 0; i < 4; ++i)
        tile[ty + i * 8][tx] = in[(size_t)(k0 + ty + i * 8) * Nn + n0 + tx];
    __syncthreads();
#pragma unroll
    for (int i = 0; i < 4; ++i)
        out[(size_t)(n0 + ty + i * 8) * K + k0 + tx] = f2bf(tile[tx][ty + i * 8]);
}

// ---------------- kernel 2: per-(nb,q,k) sbias + gate MLP ----------------
__global__ __launch_bounds__(256) void gate_sbias_kernel(const int* __restrict__ mask,
                                                         const float* __restrict__ edge,
                                                         const float* __restrict__ w1,
                                                         const float* __restrict__ b1,
                                                         const float* __restrict__ w2,
                                                         const float* __restrict__ b2,
                                                         u16* __restrict__ gate,
                                                         float* __restrict__ sbias) {
    __shared__ float w1s[64], b1s[16], w2s[128], b2s[8];
    __shared__ int nds[64];
    int t = threadIdx.x;
    int nb = blockIdx.x;
    if (t < 64) w1s[t] = w1[t];
    if (t < 16) b1s[t] = b1[t];
    if (t < 128) w2s[t] = w2[t];
    if (t < 8) b2s[t] = b2[t];
    if (t < 64) {
        int s = 0;
        const int* mr = mask + (size_t)(nb * 64 + t) * 64;
#pragma unroll 8
        for (int k = 0; k < 64; ++k) s += mr[k];
        nds[t] = (s < 1) ? 1 : 0;
    }
    __syncthreads();
#pragma unroll 1
    for (int it = 0; it < 16; ++it) {
        int p = it * 256 + t;
        int q = p >> 6, k = p & 63;
        int mv = mask[(size_t)(nb * 64 + q) * 64 + k];
        float e0, e1, e2, e3;
        if (q == k) {
            mv = max(mv, nds[q]);
            e0 = e1 = e2 = 0.f;
            e3 = 1.f;
        } else {
            const float* ep = edge + ((size_t)(nb * 64 + q) * 64 + k) * 4;
            e0 = ep[0]; e1 = ep[1]; e2 = ep[2]; e3 = ep[3];
        }
        sbias[(size_t)(nb * 64 + q) * 64 + k] = mv ? e3 : -1e30f;
        float g[8];
#pragma unroll
        for (int hh = 0; hh < 8; ++hh) g[hh] = b2s[hh];
#pragma unroll
        for (int j = 0; j < 16; ++j) {
            float hpre = e0 * w1s[j] + e1 * w1s[16 + j] + e2 * w1s[32 + j] + e3 * w1s[48 + j] + b1s[j];
            float hg = 0.5f * hpre * (1.f + erff(hpre * 0.70710678f));
#pragma unroll
            for (int hh = 0; hh < 8; ++hh) g[hh] += hg * w2s[j * 8 + hh];
        }
#pragma unroll
        for (int hh = 0; hh < 8; ++hh)
            gate[(((size_t)nb * 8 + hh) * 64 + q) * 64 + k] = f2bf(mv ? g[hh] : 0.f);
    }
}

// ---------------- kernel 3: g_block = sigmoid(x @ w_blk + b_blk) ----------------
__global__ __launch_bounds__(256) void gblock_kernel(const u16* __restrict__ xbf,
                                                     const float* __restrict__ w_blk,
                                                     const float* __restrict__ b_blk,
                                                     float* __restrict__ gbl) {
    __shared__ u16 Xs[32][520];
    __shared__ float wbs[512 * 8];
    __shared__ float bbs[8];
    int t = threadIdx.x;
    int tok0 = blockIdx.x * 32;
    for (int i = t; i < 4096; i += 256) wbs[i] = w_blk[i];
    if (t < 8) bbs[t] = b_blk[t];
    {
        int row = t >> 3, c0 = (t & 7) * 64;
        const uint4* src = (const uint4*)(xbf + (size_t)(tok0 + row) * 512 + c0);
        uint4* dst = (uint4*)(&Xs[row][c0]);
#pragma unroll
        for (int i = 0; i < 8; ++i) dst[i] = src[i];
    }
    __syncthreads();
    int row = t >> 3, h = t & 7;
    float acc = bbs[h];
#pragma unroll 8
    for (int c = 0; c < 512; ++c) acc += bf2f(Xs[row][c]) * wbs[c * 8 + h];
    gbl[(size_t)(tok0 + row) * 8 + h] = 1.f / (1.f + __expf(-acc));
}

// ---------------- kernel 4: qkv = xbf @ w_qkv^T tiles + bias (bf16 out) ----------------
__global__ __launch_bounds__(256) void qkv_gemm_kernel(const u16* __restrict__ xbf,
                                                       const u16* __restrict__ wqkvT,
                                                       const float* __restrict__ b_qkv,
                                                       u16* __restrict__ qkv) {
    int tid = threadIdx.x;
    int nt = blockIdx.x;  // 0..11
    int mt = blockIdx.y;  // 0..511
    int lane = tid & 63, l15 = lane & 15, quad = lane >> 4, wave = tid >> 6;
    int mw = mt * 128 + (wave >> 1) * 64;
    int nw = nt * 128 + (wave & 1) * 64;
    f32x4 acc[4][4];
#pragma unroll
    for (int i = 0; i < 4; ++i)
#pragma unroll
        for (int j = 0; j < 4; ++j) acc[i][j] = (f32x4){0.f, 0.f, 0.f, 0.f};
    const u16* pa[4];
    const u16* pb[4];
#pragma unroll
    for (int i = 0; i < 4; ++i) pa[i] = xbf + (size_t)(mw + i * 16 + l15) * CC;
#pragma unroll
    for (int i = 0; i < 4; ++i) pb[i] = wqkvT + (size_t)(nw + i * 16 + l15) * CC;
#pragma unroll 2
    for (int kk = 0; kk < 16; ++kk) {
        int ko = kk * 32 + quad * 8;
        bf16x8 a[4], bb[4];
#pragma unroll
        for (int i = 0; i < 4; ++i) a[i] = bc8(*(const uint4*)(pa[i] + ko));
#pragma unroll
        for (int i = 0; i < 4; ++i) bb[i] = bc8(*(const uint4*)(pb[i] + ko));
#pragma unroll
        for (int i = 0; i < 4; ++i)
#pragma unroll
            for (int j = 0; j < 4; ++j)
                acc[i][j] = __builtin_amdgcn_mfma_f32_16x16x32_bf16(a[i], bb[j], acc[i][j], 0, 0, 0);
    }
#pragma unroll
    for (int i = 0; i < 4; ++i)
#pragma unroll
        for (int j = 0; j < 4; ++j) {
            int col = nw + j * 16 + l15;
            float bp = b_qkv[col];
#pragma unroll
            for (int r = 0; r < 4; ++r) {
                int row = mw + i * 16 + quad * 4 + r;
                qkv[(size_t)row * 1536 + col] = f2bf(acc[i][j][r] + bp);
            }
        }
}

// ---------------- kernel 5: fused per-(b,nb,h) attention ----------------
__global__ __launch_bounds__(256) void attn_kernel(const u16* __restrict__ qkv,
                                                   const float* __restrict__ sbias,
                                                   const u16* __restrict__ gate,
                                                   const float* __restrict__ gbl,
                                                   u16* __restrict__ xmid) {
    __shared__ u16 VT[64 * 72], Ps[64 * 72];
    __shared__ float gl[64], vbl[64];
    int tid = threadIdx.x;
    int bid = blockIdx.x;
    int h = bid & 7, nb = (bid >> 3) & 511, b = bid >> 12;
    int lane = tid & 63, l15 = lane & 15, quad = lane >> 4, wave = tid >> 6;
    int m0 = wave * 16;
    size_t blockrow = (size_t)(b * NTOK + nb * 64);
    const u16* qbase = qkv + blockrow * 1536 + h * 64;

    // stage V transposed: VT[d][key], stride 72
    {
        int key = tid & 63, d0 = (tid >> 6) * 16;
        const uint4* vsrc = (const uint4*)(qbase + (size_t)key * 1536 + 1024 + d0);
        uint4 v0 = vsrc[0], v1 = vsrc[1];
        u16 tmp[16];
        *(uint4*)tmp = v0;
        *(uint4*)(tmp + 8) = v1;
#pragma unroll
        for (int j = 0; j < 16; ++j) VT[(d0 + j) * 72 + key] = tmp[j];
    }
    if (tid < 64) gl[tid] = gbl[(blockrow + tid) * 8 + h];
    __syncthreads();

    // v_block[d] = mean over keys of V (bias already in qkv)
    if (tid < 64) {
        float s = 0.f;
#pragma unroll 8
        for (int k = 0; k < 64; ++k) s += bf2f(VT[tid * 72 + k]);
        vbl[tid] = s * 0.015625f;
    }

    // ---- scores = Q @ K^T * 0.125 + sbias; softmax; +gate; -> Ps ----
    f32x4 sc[4];
#pragma unroll
    for (int t = 0; t < 4; ++t) sc[t] = (f32x4){0.f, 0.f, 0.f, 0.f};
#pragma unroll
    for (int kk = 0; kk < 2; ++kk) {
        bf16x8 a = bc8(*(const uint4*)(qbase + (size_t)(m0 + l15) * 1536 + kk * 32 + quad * 8));
#pragma unroll
        for (int t = 0; t < 4; ++t) {
            bf16x8 bb = bc8(*(const uint4*)(qbase + (size_t)(t * 16 + l15) * 1536 + 512 + kk * 32 + quad * 8));
            sc[t] = __builtin_amdgcn_mfma_f32_16x16x32_bf16(a, bb, sc[t], 0, 0, 0);
        }
    }
    {
        const float* sbp = sbias + (size_t)nb * 64 * 64;
#pragma unroll
        for (int r = 0; r < 4; ++r) {
            int q = m0 + quad * 4 + r;
            float mx = -3e38f;
#pragma unroll
            for (int t = 0; t < 4; ++t) {
                float v = sc[t][r] * 0.125f + sbp[q * 64 + t * 16 + l15];
                sc[t][r] = v;
                mx = fmaxf(mx, v);
            }
            mx = fmaxf(mx, __shfl_xor(mx, 1));
            mx = fmaxf(mx, __shfl_xor(mx, 2));
            mx = fmaxf(mx, __shfl_xor(mx, 4));
            mx = fmaxf(mx, __shfl_xor(mx, 8));
            float sum = 0.f;
#pragma unroll
            for (int t = 0; t < 4; ++t) {
                float p = __expf(sc[t][r] - mx);
                sc[t][r] = p;
                sum += p;
            }
            sum += __shfl_xor(sum, 1);
            sum += __shfl_xor(sum, 2);
            sum += __shfl_xor(sum, 4);
            sum += __shfl_xor(sum, 8);
            float inv = 1.f / sum;
            const u16* gp = gate + (((size_t)nb * 8 + h) * 64 + q) * 64;
#pragma unroll
            for (int t = 0; t < 4; ++t) {
                float comb = sc[t][r] * inv + bf2f(gp[t * 16 + l15]);
                Ps[q * 72 + t * 16 + l15] = f2bf(comb);
            }
        }
    }
    __syncthreads();

    // ---- x_mid = P @ V  (+ g_block * v_block) ----
    f32x4 o[4];
#pragma unroll
    for (int t = 0; t < 4; ++t) o[t] = (f32x4){0.f, 0.f, 0.f, 0.f};
#pragma unroll
    for (int kk = 0; kk < 2; ++kk) {
        bf16x8 a = *(const bf16x8*)&Ps[(m0 + l15) * 72 + kk * 32 + quad * 8];
#pragma unroll
        for (int t = 0; t < 4; ++t) {
            bf16x8 bb = *(const bf16x8*)&VT[(t * 16 + l15) * 72 + kk * 32 + quad * 8];
            o[t] = __builtin_amdgcn_mfma_f32_16x16x32_bf16(a, bb, o[t], 0, 0, 0);
        }
    }
#pragma unroll
    for (int t = 0; t < 4; ++t) {
#pragma unroll
        for (int r = 0; r < 4; ++r) {
            int q = m0 + quad * 4 + r, d = t * 16 + l15;
            float v = o[t][r] + gl[q] * vbl[d];
            xmid[(blockrow + q) * CC + h * 64 + d] = f2bf(v);
        }
    }
}

// ---------------- kernel 6: out = x_mid @ w_proj + b_proj ----------------
__global__ __launch_bounds__(256) void outproj_kernel(const u16* __restrict__ xmid,
                                                      const u16* __restrict__ wprojT,
                                                      const float* __restrict__ b_proj,
                                                      float* __restrict__ out) {
    int tid = threadIdx.x, bid = blockIdx.x;
    int mb = bid >> 2, nbk = bid & 3;
    int lane = tid & 63, l15 = lane & 15, quad = lane >> 4, wave = tid >> 6;
    int mw = mb * 128 + (wave >> 1) * 64;
    int nw = nbk * 128 + (wave & 1) * 64;
    f32x4 acc[4][4];
#pragma unroll
    for (int mt = 0; mt < 4; ++mt)
#pragma unroll
        for (int nt = 0; nt < 4; ++nt) acc[mt][nt] = (f32x4){0.f, 0.f, 0.f, 0.f};
    const u16* pa[4];
    const u16* pb[4];
#pragma unroll
    for (int mt = 0; mt < 4; ++mt) pa[mt] = xmid + (size_t)(mw + mt * 16 + l15) * CC;
#pragma unroll
    for (int nt = 0; nt < 4; ++nt) pb[nt] = wprojT + (size_t)(nw + nt * 16 + l15) * CC;
#pragma unroll 2
    for (int kk = 0; kk < 16; ++kk) {
        int ko = kk * 32 + quad * 8;
        bf16x8 a[4], bb[4];
#pragma unroll
        for (int mt = 0; mt < 4; ++mt) a[mt] = bc8(*(const uint4*)(pa[mt] + ko));
#pragma unroll
        for (int nt = 0; nt < 4; ++nt) bb[nt] = bc8(*(const uint4*)(pb[nt] + ko));
#pragma unroll
        for (int mt = 0; mt < 4; ++mt)
#pragma unroll
            for (int nt = 0; nt < 4; ++nt)
                acc[mt][nt] = __builtin_amdgcn_mfma_f32_16x16x32_bf16(a[mt], bb[nt], acc[mt][nt], 0, 0, 0);
    }
#pragma unroll
    for (int mt = 0; mt < 4; ++mt)
#pragma unroll
        for (int nt = 0; nt < 4; ++nt) {
            int col = nw + nt * 16 + l15;
            float bp = b_proj[col];
#pragma unroll
            for (int r = 0; r < 4; ++r) {
                int row = mw + mt * 16 + quad * 4 + r;
                out[(size_t)row * CC + col] = acc[mt][nt][r] + bp;
            }
        }
}

extern "C" void kernel_launch(void* const* d_in, const int* in_sizes, int n_in,
                              void* d_out, int out_size, void* d_ws, size_t ws_size,
                              hipStream_t stream) {
    const float* x = (const float*)d_in[0];
    const int* attn_mask = (const int*)d_in[1];
    const float* edge = (const float*)d_in[2];
    const float* w_qkv = (const float*)d_in[3];
    const float* b_qkv = (const float*)d_in[4];
    const float* w_proj = (const float*)d_in[5];
    const float* b_proj = (const float*)d_in[6];
    const float* w_eg1 = (const float*)d_in[7];
    const float* b_eg1 = (const float*)d_in[8];
    const float* w_eg2 = (const float*)d_in[9];
    const float* b_eg2 = (const float*)d_in[10];
    const float* w_blk = (const float*)d_in[11];
    const float* b_blk = (const float*)d_in[12];
    float* out = (float*)d_out;

    char* ws = (char*)d_ws;
    // xmid aliases xbf: xbf consumed by gblock+qkv_gemm before attn writes xmid.
    u16* xbf = (u16*)ws;                            // 67108864 bytes
    u16* xmid = (u16*)ws;                           // alias
    u16* qkv = (u16*)(ws + 67108864);               // 65536*1536*2 = 201326592
    u16* gate = (u16*)(ws + 268435456);             // 33554432
    float* sbias = (float*)(ws + 301989888);        // 8388608
    u16* wqkvT = (u16*)(ws + 310378496);            // 1572864
    u16* wprojT = (u16*)(ws + 311951360);           // 524288
    float* gbl = (float*)(ws + 312475648);          // 65536*8*4 = 2097152

    convert_x_kernel<<<16384, 256, 0, stream>>>(x, xbf);
    transpose_bf16_kernel<<<dim3(48, 16), 256, 0, stream>>>(w_qkv, wqkvT, 512, 1536);
    transpose_bf16_kernel<<<dim3(16, 16), 256, 0, stream>>>(w_proj, wprojT, 512, 512);
    gate_sbias_kernel<<<512, 256, 0, stream>>>(attn_mask, edge, w_eg1, b_eg1, w_eg2, b_eg2,
                                               gate, sbias);
    gblock_kernel<<<2048, 256, 0, stream>>>(xbf, w_blk, b_blk, gbl);
    qkv_gemm_kernel<<<dim3(12, 512), 256, 0, stream>>>(xbf, wqkvT, b_qkv, qkv);
    attn_kernel<<<8192, 256, 0, stream>>>(qkv, sbias, gate, gbl, xmid);
    outproj_kernel<<<2048, 256, 0, stream>>>(xmid, wprojT, b_proj, out);
}

// Round 3
// 717.234 us; speedup vs baseline: 1.8431x; 1.3917x over previous
//
#include <hip/hip_runtime.h>

typedef unsigned short u16;
typedef __attribute__((ext_vector_type(8))) short bf16x8;
typedef __attribute__((ext_vector_type(4))) float f32x4;

#define NTOK 32768
#define CC 512
#define HH 8
#define LL 64
#define NBLK 512

__device__ __forceinline__ u16 f2bf(float f) {
    unsigned int u = __float_as_uint(f);
    unsigned int r = u + 0x7fffu + ((u >> 16) & 1u);
    return (u16)(r >> 16);
}
__device__ __forceinline__ float bf2f(u16 h) {
    return __uint_as_float(((unsigned int)h) << 16);
}
__device__ __forceinline__ bf16x8 bc8(uint4 v) {
    return __builtin_bit_cast(bf16x8, v);
}
__device__ __forceinline__ void dma16(const u16* g, u16* l) {
    __builtin_amdgcn_global_load_lds((const __attribute__((address_space(1))) void*)g,
                                     (__attribute__((address_space(3))) void*)l, 16, 0, 0);
}

// ---------------- kernel 0: x fp32 -> bf16 ----------------
__global__ __launch_bounds__(256) void convert_x_kernel(const float* __restrict__ x,
                                                        u16* __restrict__ xbf) {
    size_t i = ((size_t)blockIdx.x * 256 + threadIdx.x) * 8;
    const float4* p = (const float4*)(x + i);
    float4 a = p[0], b = p[1];
    uint4 o;
    o.x = (unsigned)f2bf(a.x) | ((unsigned)f2bf(a.y) << 16);
    o.y = (unsigned)f2bf(a.z) | ((unsigned)f2bf(a.w) << 16);
    o.z = (unsigned)f2bf(b.x) | ((unsigned)f2bf(b.y) << 16);
    o.w = (unsigned)f2bf(b.z) | ((unsigned)f2bf(b.w) << 16);
    *(uint4*)(xbf + i) = o;
}

// ---------------- kernel 1: transpose fp32 [K][Nn] -> bf16 [Nn][K] ----------------
__global__ __launch_bounds__(256) void transpose_bf16_kernel(const float* __restrict__ in,
                                                             u16* __restrict__ out,
                                                             int K, int Nn) {
    __shared__ float tile[32][33];
    int n0 = blockIdx.x * 32, k0 = blockIdx.y * 32;
    int tx = threadIdx.x & 31, ty = threadIdx.x >> 5;
#pragma unroll
    for (int i = 0; i < 4; ++i)
        tile[ty + i * 8][tx] = in[(size_t)(k0 + ty + i * 8) * Nn + n0 + tx];
    __syncthreads();
#pragma unroll
    for (int i = 0; i < 4; ++i)
        out[(size_t)(n0 + ty + i * 8) * K + k0 + tx] = f2bf(tile[tx][ty + i * 8]);
}

// ---------------- kernel 2: per-(nb,q,k) sbias + gate MLP ----------------
__global__ __launch_bounds__(256) void gate_sbias_kernel(const int* __restrict__ mask,
                                                         const float* __restrict__ edge,
                                                         const float* __restrict__ w1,
                                                         const float* __restrict__ b1,
                                                         const float* __restrict__ w2,
                                                         const float* __restrict__ b2,
                                                         u16* __restrict__ gate,
                                                         float* __restrict__ sbias) {
    __shared__ float w1s[64], b1s[16], w2s[128], b2s[8];
    __shared__ int nds[64];
    int t = threadIdx.x;
    int nb = blockIdx.x;
    if (t < 64) w1s[t] = w1[t];
    if (t < 16) b1s[t] = b1[t];
    if (t < 128) w2s[t] = w2[t];
    if (t < 8) b2s[t] = b2[t];
    if (t < 64) {
        int s = 0;
        const int* mr = mask + (size_t)(nb * 64 + t) * 64;
#pragma unroll 8
        for (int k = 0; k < 64; ++k) s += mr[k];
        nds[t] = (s < 1) ? 1 : 0;
    }
    __syncthreads();
#pragma unroll 1
    for (int it = 0; it < 16; ++it) {
        int p = it * 256 + t;
        int q = p >> 6, k = p & 63;
        int mv = mask[(size_t)(nb * 64 + q) * 64 + k];
        float e0, e1, e2, e3;
        if (q == k) {
            mv = max(mv, nds[q]);
            e0 = e1 = e2 = 0.f;
            e3 = 1.f;
        } else {
            const float* ep = edge + ((size_t)(nb * 64 + q) * 64 + k) * 4;
            e0 = ep[0]; e1 = ep[1]; e2 = ep[2]; e3 = ep[3];
        }
        sbias[(size_t)(nb * 64 + q) * 64 + k] = mv ? e3 : -1e30f;
        float g[8];
#pragma unroll
        for (int hh = 0; hh < 8; ++hh) g[hh] = b2s[hh];
#pragma unroll
        for (int j = 0; j < 16; ++j) {
            float hpre = e0 * w1s[j] + e1 * w1s[16 + j] + e2 * w1s[32 + j] + e3 * w1s[48 + j] + b1s[j];
            float hg = 0.5f * hpre * (1.f + erff(hpre * 0.70710678f));
#pragma unroll
            for (int hh = 0; hh < 8; ++hh) g[hh] += hg * w2s[j * 8 + hh];
        }
#pragma unroll
        for (int hh = 0; hh < 8; ++hh)
            gate[(((size_t)nb * 8 + hh) * 64 + q) * 64 + k] = f2bf(mv ? g[hh] : 0.f);
    }
}

// ---------------- kernel 3: g_block = sigmoid(x @ w_blk + b_blk) ----------------
__global__ __launch_bounds__(256) void gblock_kernel(const u16* __restrict__ xbf,
                                                     const float* __restrict__ w_blk,
                                                     const float* __restrict__ b_blk,
                                                     float* __restrict__ gbl) {
    __shared__ u16 Xs[32][520];
    __shared__ float wbs[512 * 8];
    __shared__ float bbs[8];
    int t = threadIdx.x;
    int tok0 = blockIdx.x * 32;
    for (int i = t; i < 4096; i += 256) wbs[i] = w_blk[i];
    if (t < 8) bbs[t] = b_blk[t];
    {
        int row = t >> 3, c0 = (t & 7) * 64;
        const uint4* src = (const uint4*)(xbf + (size_t)(tok0 + row) * 512 + c0);
        uint4* dst = (uint4*)(&Xs[row][c0]);
#pragma unroll
        for (int i = 0; i < 8; ++i) dst[i] = src[i];
    }
    __syncthreads();
    int row = t >> 3, h = t & 7;
    float acc = bbs[h];
#pragma unroll 8
    for (int c = 0; c < 512; ++c) acc += bf2f(Xs[row][c]) * wbs[c * 8 + h];
    gbl[(size_t)(tok0 + row) * 8 + h] = 1.f / (1.f + __expf(-acc));
}

// ---------------- m97-style 128x128 GEMM: C = A(MxK) @ B^T(NxK), bf16 out ----------------
// A rows [m0..m0+128), B rows (= out cols) [n0..n0+128), K=512, BK=64.
// LDS layout: As/Bs [128][64] bf16, 16B chunk c of row r stored at slot c^(r&7)
// (XOR swizzle applied on the GLOBAL source address; DMA lane->LDS slot is fixed).
__global__ __launch_bounds__(256) void qkv_gemm_kernel(const u16* __restrict__ xbf,
                                                       const u16* __restrict__ wqkvT,
                                                       const float* __restrict__ b_qkv,
                                                       u16* __restrict__ qkv) {
    __shared__ __align__(16) u16 As[128 * 64], Bs[128 * 64];
    int tid = threadIdx.x;
    int n0 = blockIdx.x * 128;  // 0..11
    int m0 = blockIdx.y * 128;  // 0..511
    int lane = tid & 63, l15 = lane & 15, quad = lane >> 4, wave = tid >> 6;
    int r8 = lane >> 3, jch = lane & 7;
    int js = jch ^ r8;  // swizzled source chunk
    int mwl = (wave >> 1) * 64, nwl = (wave & 1) * 64;
    int sw = l15 & 7;

    f32x4 acc[4][4];
#pragma unroll
    for (int i = 0; i < 4; ++i)
#pragma unroll
        for (int j = 0; j < 4; ++j) acc[i][j] = (f32x4){0.f, 0.f, 0.f, 0.f};

    int arow[4], brow[4];
#pragma unroll
    for (int i = 0; i < 4; ++i) arow[i] = (mwl + i * 16 + l15) * 64;
#pragma unroll
    for (int j = 0; j < 4; ++j) brow[j] = (nwl + j * 16 + l15) * 64;

    const u16* gA = xbf + (size_t)(m0 + wave * 32 + r8) * CC + js * 8;
    const u16* gB = wqkvT + (size_t)(n0 + wave * 32 + r8) * CC + js * 8;
    u16* lA = As + wave * 32 * 64;
    u16* lB = Bs + wave * 32 * 64;

    for (int kt = 0; kt < 8; ++kt) {
        int k0 = kt * 64;
#pragma unroll
        for (int t = 0; t < 4; ++t) {
            dma16(gA + (size_t)t * 8 * CC + k0, lA + t * 8 * 64);
            dma16(gB + (size_t)t * 8 * CC + k0, lB + t * 8 * 64);
        }
        __syncthreads();
#pragma unroll
        for (int kk = 0; kk < 2; ++kk) {
            int ch = ((kk * 4 + quad) ^ sw) * 8;
            bf16x8 a[4], bb[4];
#pragma unroll
            for (int i = 0; i < 4; ++i) a[i] = *(const bf16x8*)&As[arow[i] + ch];
#pragma unroll
            for (int j = 0; j < 4; ++j) bb[j] = *(const bf16x8*)&Bs[brow[j] + ch];
#pragma unroll
            for (int i = 0; i < 4; ++i)
#pragma unroll
                for (int j = 0; j < 4; ++j)
                    acc[i][j] = __builtin_amdgcn_mfma_f32_16x16x32_bf16(a[i], bb[j], acc[i][j], 0, 0, 0);
        }
        __syncthreads();
    }
#pragma unroll
    for (int i = 0; i < 4; ++i)
#pragma unroll
        for (int j = 0; j < 4; ++j) {
            int col = n0 + nwl + j * 16 + l15;
            float bp = b_qkv[col];
#pragma unroll
            for (int r = 0; r < 4; ++r) {
                int row = m0 + mwl + i * 16 + quad * 4 + r;
                qkv[(size_t)row * 1536 + col] = f2bf(acc[i][j][r] + bp);
            }
        }
}

// ---------------- out = x_mid @ w_proj + b_proj (fp32 out), same structure ----------------
__global__ __launch_bounds__(256) void outproj_kernel(const u16* __restrict__ xmid,
                                                      const u16* __restrict__ wprojT,
                                                      const float* __restrict__ b_proj,
                                                      float* __restrict__ out) {
    __shared__ __align__(16) u16 As[128 * 64], Bs[128 * 64];
    int tid = threadIdx.x;
    int n0 = blockIdx.x * 128;  // 0..3
    int m0 = blockIdx.y * 128;  // 0..511
    int lane = tid & 63, l15 = lane & 15, quad = lane >> 4, wave = tid >> 6;
    int r8 = lane >> 3, jch = lane & 7;
    int js = jch ^ r8;
    int mwl = (wave >> 1) * 64, nwl = (wave & 1) * 64;
    int sw = l15 & 7;

    f32x4 acc[4][4];
#pragma unroll
    for (int i = 0; i < 4; ++i)
#pragma unroll
        for (int j = 0; j < 4; ++j) acc[i][j] = (f32x4){0.f, 0.f, 0.f, 0.f};

    int arow[4], brow[4];
#pragma unroll
    for (int i = 0; i < 4; ++i) arow[i] = (mwl + i * 16 + l15) * 64;
#pragma unroll
    for (int j = 0; j < 4; ++j) brow[j] = (nwl + j * 16 + l15) * 64;

    const u16* gA = xmid + (size_t)(m0 + wave * 32 + r8) * CC + js * 8;
    const u16* gB = wprojT + (size_t)(n0 + wave * 32 + r8) * CC + js * 8;
    u16* lA = As + wave * 32 * 64;
    u16* lB = Bs + wave * 32 * 64;

    for (int kt = 0; kt < 8; ++kt) {
        int k0 = kt * 64;
#pragma unroll
        for (int t = 0; t < 4; ++t) {
            dma16(gA + (size_t)t * 8 * CC + k0, lA + t * 8 * 64);
            dma16(gB + (size_t)t * 8 * CC + k0, lB + t * 8 * 64);
        }
        __syncthreads();
#pragma unroll
        for (int kk = 0; kk < 2; ++kk) {
            int ch = ((kk * 4 + quad) ^ sw) * 8;
            bf16x8 a[4], bb[4];
#pragma unroll
            for (int i = 0; i < 4; ++i) a[i] = *(const bf16x8*)&As[arow[i] + ch];
#pragma unroll
            for (int j = 0; j < 4; ++j) bb[j] = *(const bf16x8*)&Bs[brow[j] + ch];
#pragma unroll
            for (int i = 0; i < 4; ++i)
#pragma unroll
                for (int j = 0; j < 4; ++j)
                    acc[i][j] = __builtin_amdgcn_mfma_f32_16x16x32_bf16(a[i], bb[j], acc[i][j], 0, 0, 0);
        }
        __syncthreads();
    }
#pragma unroll
    for (int i = 0; i < 4; ++i)
#pragma unroll
        for (int j = 0; j < 4; ++j) {
            int col = n0 + nwl + j * 16 + l15;
            float bp = b_proj[col];
#pragma unroll
            for (int r = 0; r < 4; ++r) {
                int row = m0 + mwl + i * 16 + quad * 4 + r;
                out[(size_t)row * CC + col] = acc[i][j][r] + bp;
            }
        }
}

// ---------------- fused per-(b,nb,h) attention ----------------
__global__ __launch_bounds__(256) void attn_kernel(const u16* __restrict__ qkv,
                                                   const float* __restrict__ sbias,
                                                   const u16* __restrict__ gate,
                                                   const float* __restrict__ gbl,
                                                   u16* __restrict__ xmid) {
    __shared__ u16 VT[64 * 72], Ps[64 * 72];
    __shared__ float gl[64], vbl[64];
    int tid = threadIdx.x;
    int bid = blockIdx.x;
    int h = bid & 7, nb = (bid >> 3) & 511, b = bid >> 12;
    int lane = tid & 63, l15 = lane & 15, quad = lane >> 4, wave = tid >> 6;
    int m0 = wave * 16;
    size_t blockrow = (size_t)(b * NTOK + nb * 64);
    const u16* qbase = qkv + blockrow * 1536 + h * 64;

    {
        int key = tid & 63, d0 = (tid >> 6) * 16;
        const uint4* vsrc = (const uint4*)(qbase + (size_t)key * 1536 + 1024 + d0);
        uint4 v0 = vsrc[0], v1 = vsrc[1];
        u16 tmp[16];
        *(uint4*)tmp = v0;
        *(uint4*)(tmp + 8) = v1;
#pragma unroll
        for (int j = 0; j < 16; ++j) VT[(d0 + j) * 72 + key] = tmp[j];
    }
    if (tid < 64) gl[tid] = gbl[(blockrow + tid) * 8 + h];
    __syncthreads();

    if (tid < 64) {
        float s = 0.f;
#pragma unroll 8
        for (int k = 0; k < 64; ++k) s += bf2f(VT[tid * 72 + k]);
        vbl[tid] = s * 0.015625f;
    }

    f32x4 sc[4];
#pragma unroll
    for (int t = 0; t < 4; ++t) sc[t] = (f32x4){0.f, 0.f, 0.f, 0.f};
#pragma unroll
    for (int kk = 0; kk < 2; ++kk) {
        bf16x8 a = bc8(*(const uint4*)(qbase + (size_t)(m0 + l15) * 1536 + kk * 32 + quad * 8));
#pragma unroll
        for (int t = 0; t < 4; ++t) {
            bf16x8 bb = bc8(*(const uint4*)(qbase + (size_t)(t * 16 + l15) * 1536 + 512 + kk * 32 + quad * 8));
            sc[t] = __builtin_amdgcn_mfma_f32_16x16x32_bf16(a, bb, sc[t], 0, 0, 0);
        }
    }
    {
        const float* sbp = sbias + (size_t)nb * 64 * 64;
#pragma unroll
        for (int r = 0; r < 4; ++r) {
            int q = m0 + quad * 4 + r;
            float mx = -3e38f;
#pragma unroll
            for (int t = 0; t < 4; ++t) {
                float v = sc[t][r] * 0.125f + sbp[q * 64 + t * 16 + l15];
                sc[t][r] = v;
                mx = fmaxf(mx, v);
            }
            mx = fmaxf(mx, __shfl_xor(mx, 1));
            mx = fmaxf(mx, __shfl_xor(mx, 2));
            mx = fmaxf(mx, __shfl_xor(mx, 4));
            mx = fmaxf(mx, __shfl_xor(mx, 8));
            float sum = 0.f;
#pragma unroll
            for (int t = 0; t < 4; ++t) {
                float p = __expf(sc[t][r] - mx);
                sc[t][r] = p;
                sum += p;
            }
            sum += __shfl_xor(sum, 1);
            sum += __shfl_xor(sum, 2);
            sum += __shfl_xor(sum, 4);
            sum += __shfl_xor(sum, 8);
            float inv = 1.f / sum;
            const u16* gp = gate + (((size_t)nb * 8 + h) * 64 + q) * 64;
#pragma unroll
            for (int t = 0; t < 4; ++t) {
                float comb = sc[t][r] * inv + bf2f(gp[t * 16 + l15]);
                Ps[q * 72 + t * 16 + l15] = f2bf(comb);
            }
        }
    }
    __syncthreads();

    f32x4 o[4];
#pragma unroll
    for (int t = 0; t < 4; ++t) o[t] = (f32x4){0.f, 0.f, 0.f, 0.f};
#pragma unroll
    for (int kk = 0; kk < 2; ++kk) {
        bf16x8 a = *(const bf16x8*)&Ps[(m0 + l15) * 72 + kk * 32 + quad * 8];
#pragma unroll
        for (int t = 0; t < 4; ++t) {
            bf16x8 bb = *(const bf16x8*)&VT[(t * 16 + l15) * 72 + kk * 32 + quad * 8];
            o[t] = __builtin_amdgcn_mfma_f32_16x16x32_bf16(a, bb, o[t], 0, 0, 0);
        }
    }
#pragma unroll
    for (int t = 0; t < 4; ++t) {
#pragma unroll
        for (int r = 0; r < 4; ++r) {
            int q = m0 + quad * 4 + r, d = t * 16 + l15;
            float v = o[t][r] + gl[q] * vbl[d];
            xmid[(blockrow + q) * CC + h * 64 + d] = f2bf(v);
        }
    }
}

extern "C" void kernel_launch(void* const* d_in, const int* in_sizes, int n_in,
                              void* d_out, int out_size, void* d_ws, size_t ws_size,
                              hipStream_t stream) {
    const float* x = (const float*)d_in[0];
    const int* attn_mask = (const int*)d_in[1];
    const float* edge = (const float*)d_in[2];
    const float* w_qkv = (const float*)d_in[3];
    const float* b_qkv = (const float*)d_in[4];
    const float* w_proj = (const float*)d_in[5];
    const float* b_proj = (const float*)d_in[6];
    const float* w_eg1 = (const float*)d_in[7];
    const float* b_eg1 = (const float*)d_in[8];
    const float* w_eg2 = (const float*)d_in[9];
    const float* b_eg2 = (const float*)d_in[10];
    const float* w_blk = (const float*)d_in[11];
    const float* b_blk = (const float*)d_in[12];
    float* out = (float*)d_out;

    char* ws = (char*)d_ws;
    u16* xbf = (u16*)ws;                            // 67108864 bytes
    u16* xmid = (u16*)ws;                           // alias (xbf consumed before attn writes)
    u16* qkv = (u16*)(ws + 67108864);               // 201326592
    u16* gate = (u16*)(ws + 268435456);             // 33554432
    float* sbias = (float*)(ws + 301989888);        // 8388608
    u16* wqkvT = (u16*)(ws + 310378496);            // 1572864
    u16* wprojT = (u16*)(ws + 311951360);           // 524288
    float* gbl = (float*)(ws + 312475648);          // 2097152

    convert_x_kernel<<<16384, 256, 0, stream>>>(x, xbf);
    transpose_bf16_kernel<<<dim3(48, 16), 256, 0, stream>>>(w_qkv, wqkvT, 512, 1536);
    transpose_bf16_kernel<<<dim3(16, 16), 256, 0, stream>>>(w_proj, wprojT, 512, 512);
    gate_sbias_kernel<<<512, 256, 0, stream>>>(attn_mask, edge, w_eg1, b_eg1, w_eg2, b_eg2,
                                               gate, sbias);
    gblock_kernel<<<2048, 256, 0, stream>>>(xbf, w_blk, b_blk, gbl);
    qkv_gemm_kernel<<<dim3(12, 512), 256, 0, stream>>>(xbf, wqkvT, b_qkv, qkv);
    attn_kernel<<<8192, 256, 0, stream>>>(qkv, sbias, gate, gbl, xmid);
    outproj_kernel<<<dim3(4, 512), 256, 0, stream>>>(xmid, wprojT, b_proj, out);
}

// Round 4
// 715.150 us; speedup vs baseline: 1.8484x; 1.0029x over previous
//
#include <hip/hip_runtime.h>

typedef unsigned short u16;
typedef __attribute__((ext_vector_type(8))) short bf16x8;
typedef __attribute__((ext_vector_type(4))) float f32x4;

#define NTOK 32768
#define CC 512
#define HH 8
#define LL 64
#define NBLK 512

__device__ __forceinline__ u16 f2bf(float f) {
    unsigned int u = __float_as_uint(f);
    unsigned int r = u + 0x7fffu + ((u >> 16) & 1u);
    return (u16)(r >> 16);
}
__device__ __forceinline__ float bf2f(u16 h) {
    return __uint_as_float(((unsigned int)h) << 16);
}
__device__ __forceinline__ bf16x8 bc8(uint4 v) {
    return __builtin_bit_cast(bf16x8, v);
}
__device__ __forceinline__ void dma16(const u16* g, u16* l) {
    __builtin_amdgcn_global_load_lds((const __attribute__((address_space(1))) void*)g,
                                     (__attribute__((address_space(3))) void*)l, 16, 0, 0);
}

// ---------------- kernel 0: x fp32 -> bf16, fused g_block GEMV ----------------
// 4 tokens per block (one per wave). Each thread covers 8 contiguous cols of its
// token; partial dot for all 8 heads of w_blk, wave-butterfly reduce.
__global__ __launch_bounds__(256) void convert_gblock_kernel(const float* __restrict__ x,
                                                             u16* __restrict__ xbf,
                                                             const float* __restrict__ w_blk,
                                                             const float* __restrict__ b_blk,
                                                             float* __restrict__ gbl) {
    __shared__ float wbs[4608];  // w_blk[c][h] at wbs[c*8+h + (c>>3)] (bank swizzle pad)
    int tid = threadIdx.x;
    for (int i = tid; i < 4096; i += 256) wbs[i + (i >> 6)] = w_blk[i];
    size_t tok = (size_t)blockIdx.x * 4 + (tid >> 6);
    int lane = tid & 63;
    int c0 = lane * 8;
    const float4* p = (const float4*)(x + tok * CC + c0);
    float4 a = p[0], b = p[1];
    uint4 o;
    o.x = (unsigned)f2bf(a.x) | ((unsigned)f2bf(a.y) << 16);
    o.y = (unsigned)f2bf(a.z) | ((unsigned)f2bf(a.w) << 16);
    o.z = (unsigned)f2bf(b.x) | ((unsigned)f2bf(b.y) << 16);
    o.w = (unsigned)f2bf(b.z) | ((unsigned)f2bf(b.w) << 16);
    *(uint4*)(xbf + tok * CC + c0) = o;
    float xv[8] = {a.x, a.y, a.z, a.w, b.x, b.y, b.z, b.w};
    __syncthreads();
    float acc[8];
#pragma unroll
    for (int h = 0; h < 8; ++h) acc[h] = 0.f;
#pragma unroll
    for (int j = 0; j < 8; ++j) {
        const float* wr = &wbs[(c0 + j) * 8 + lane];  // (c0+j)>>3 == lane for j<8
#pragma unroll
        for (int h = 0; h < 8; ++h) acc[h] += xv[j] * wr[h];
    }
#pragma unroll
    for (int h = 0; h < 8; ++h) {
#pragma unroll
        for (int off = 1; off < 64; off <<= 1) acc[h] += __shfl_xor(acc[h], off);
    }
    float v = acc[0];
#pragma unroll
    for (int h = 1; h < 8; ++h) v = (lane == h) ? acc[h] : v;
    if (lane < 8) gbl[tok * 8 + lane] = 1.f / (1.f + __expf(-(v + b_blk[lane])));
}

// ---------------- kernel 1: transpose fp32 [K][Nn] -> bf16 [Nn][K] ----------------
__global__ __launch_bounds__(256) void transpose_bf16_kernel(const float* __restrict__ in,
                                                             u16* __restrict__ out,
                                                             int K, int Nn) {
    __shared__ float tile[32][33];
    int n0 = blockIdx.x * 32, k0 = blockIdx.y * 32;
    int tx = threadIdx.x & 31, ty = threadIdx.x >> 5;
#pragma unroll
    for (int i = 0; i < 4; ++i)
        tile[ty + i * 8][tx] = in[(size_t)(k0 + ty + i * 8) * Nn + n0 + tx];
    __syncthreads();
#pragma unroll
    for (int i = 0; i < 4; ++i)
        out[(size_t)(n0 + ty + i * 8) * K + k0 + tx] = f2bf(tile[tx][ty + i * 8]);
}

// ---------------- kernel 2: sbias2/gate2 in MFMA C-fragment layout ----------------
// packed index within a (nb,q) row: pk = (k&15)*4 + (k>>4)  (so [l15][t] is 8B-contig)
__global__ __launch_bounds__(256) void gate_sbias_kernel(const int* __restrict__ mask,
                                                         const float* __restrict__ edge,
                                                         const float* __restrict__ w1,
                                                         const float* __restrict__ b1,
                                                         const float* __restrict__ w2,
                                                         const float* __restrict__ b2,
                                                         u16* __restrict__ gate2,
                                                         u16* __restrict__ sbias2) {
    __shared__ float w1s[64], b1s[16], w2s[128], b2s[8];
    __shared__ int nds[64];
    int t = threadIdx.x;
    int nb = blockIdx.x;
    if (t < 64) w1s[t] = w1[t];
    if (t < 16) b1s[t] = b1[t];
    if (t < 128) w2s[t] = w2[t];
    if (t < 8) b2s[t] = b2[t];
    if (t < 64) {
        int s = 0;
        const int* mr = mask + (size_t)(nb * 64 + t) * 64;
#pragma unroll 8
        for (int k = 0; k < 64; ++k) s += mr[k];
        nds[t] = (s < 1) ? 1 : 0;
    }
    __syncthreads();
#pragma unroll 1
    for (int it = 0; it < 16; ++it) {
        int p = it * 256 + t;
        int q = p >> 6, k = p & 63;
        int pk = (k & 15) * 4 + (k >> 4);
        int mv = mask[(size_t)(nb * 64 + q) * 64 + k];
        float e0, e1, e2, e3;
        if (q == k) {
            mv = max(mv, nds[q]);
            e0 = e1 = e2 = 0.f;
            e3 = 1.f;
        } else {
            const float* ep = edge + ((size_t)(nb * 64 + q) * 64 + k) * 4;
            e0 = ep[0]; e1 = ep[1]; e2 = ep[2]; e3 = ep[3];
        }
        sbias2[(size_t)(nb * 64 + q) * 64 + pk] = f2bf(mv ? e3 : -1e30f);
        float g[8];
#pragma unroll
        for (int hh = 0; hh < 8; ++hh) g[hh] = b2s[hh];
#pragma unroll
        for (int j = 0; j < 16; ++j) {
            float hpre = e0 * w1s[j] + e1 * w1s[16 + j] + e2 * w1s[32 + j] + e3 * w1s[48 + j] + b1s[j];
            float hg = 0.5f * hpre * (1.f + erff(hpre * 0.70710678f));
#pragma unroll
            for (int hh = 0; hh < 8; ++hh) g[hh] += hg * w2s[j * 8 + hh];
        }
#pragma unroll
        for (int hh = 0; hh < 8; ++hh)
            gate2[(((size_t)nb * 8 + hh) * 64 + q) * 64 + pk] = f2bf(mv ? g[hh] : 0.f);
    }
}

// ---------------- m97-style 128x128 GEMM: qkv = xbf @ wqkvT^T + b (bf16 out) ----------------
__global__ __launch_bounds__(256) void qkv_gemm_kernel(const u16* __restrict__ xbf,
                                                       const u16* __restrict__ wqkvT,
                                                       const float* __restrict__ b_qkv,
                                                       u16* __restrict__ qkv) {
    __shared__ __align__(16) u16 As[128 * 64], Bs[128 * 64];
    int tid = threadIdx.x;
    int n0 = blockIdx.x * 128;
    int m0 = blockIdx.y * 128;
    int lane = tid & 63, l15 = lane & 15, quad = lane >> 4, wave = tid >> 6;
    int r8 = lane >> 3, jch = lane & 7;
    int js = jch ^ r8;
    int mwl = (wave >> 1) * 64, nwl = (wave & 1) * 64;
    int sw = l15 & 7;

    f32x4 acc[4][4];
#pragma unroll
    for (int i = 0; i < 4; ++i)
#pragma unroll
        for (int j = 0; j < 4; ++j) acc[i][j] = (f32x4){0.f, 0.f, 0.f, 0.f};

    int arow[4], brow[4];
#pragma unroll
    for (int i = 0; i < 4; ++i) arow[i] = (mwl + i * 16 + l15) * 64;
#pragma unroll
    for (int j = 0; j < 4; ++j) brow[j] = (nwl + j * 16 + l15) * 64;

    const u16* gA = xbf + (size_t)(m0 + wave * 32 + r8) * CC + js * 8;
    const u16* gB = wqkvT + (size_t)(n0 + wave * 32 + r8) * CC + js * 8;
    u16* lA = As + wave * 32 * 64;
    u16* lB = Bs + wave * 32 * 64;

    for (int kt = 0; kt < 8; ++kt) {
        int k0 = kt * 64;
#pragma unroll
        for (int t = 0; t < 4; ++t) {
            dma16(gA + (size_t)t * 8 * CC + k0, lA + t * 8 * 64);
            dma16(gB + (size_t)t * 8 * CC + k0, lB + t * 8 * 64);
        }
        __syncthreads();
#pragma unroll
        for (int kk = 0; kk < 2; ++kk) {
            int ch = ((kk * 4 + quad) ^ sw) * 8;
            bf16x8 a[4], bb[4];
#pragma unroll
            for (int i = 0; i < 4; ++i) a[i] = *(const bf16x8*)&As[arow[i] + ch];
#pragma unroll
            for (int j = 0; j < 4; ++j) bb[j] = *(const bf16x8*)&Bs[brow[j] + ch];
#pragma unroll
            for (int i = 0; i < 4; ++i)
#pragma unroll
                for (int j = 0; j < 4; ++j)
                    acc[i][j] = __builtin_amdgcn_mfma_f32_16x16x32_bf16(a[i], bb[j], acc[i][j], 0, 0, 0);
        }
        __syncthreads();
    }
#pragma unroll
    for (int i = 0; i < 4; ++i)
#pragma unroll
        for (int j = 0; j < 4; ++j) {
            int col = n0 + nwl + j * 16 + l15;
            float bp = b_qkv[col];
#pragma unroll
            for (int r = 0; r < 4; ++r) {
                int row = m0 + mwl + i * 16 + quad * 4 + r;
                qkv[(size_t)row * 1536 + col] = f2bf(acc[i][j][r] + bp);
            }
        }
}

// ---------------- out = x_mid @ w_proj + b_proj (fp32 out) ----------------
__global__ __launch_bounds__(256) void outproj_kernel(const u16* __restrict__ xmid,
                                                      const u16* __restrict__ wprojT,
                                                      const float* __restrict__ b_proj,
                                                      float* __restrict__ out) {
    __shared__ __align__(16) u16 As[128 * 64], Bs[128 * 64];
    int tid = threadIdx.x;
    int n0 = blockIdx.x * 128;
    int m0 = blockIdx.y * 128;
    int lane = tid & 63, l15 = lane & 15, quad = lane >> 4, wave = tid >> 6;
    int r8 = lane >> 3, jch = lane & 7;
    int js = jch ^ r8;
    int mwl = (wave >> 1) * 64, nwl = (wave & 1) * 64;
    int sw = l15 & 7;

    f32x4 acc[4][4];
#pragma unroll
    for (int i = 0; i < 4; ++i)
#pragma unroll
        for (int j = 0; j < 4; ++j) acc[i][j] = (f32x4){0.f, 0.f, 0.f, 0.f};

    int arow[4], brow[4];
#pragma unroll
    for (int i = 0; i < 4; ++i) arow[i] = (mwl + i * 16 + l15) * 64;
#pragma unroll
    for (int j = 0; j < 4; ++j) brow[j] = (nwl + j * 16 + l15) * 64;

    const u16* gA = xmid + (size_t)(m0 + wave * 32 + r8) * CC + js * 8;
    const u16* gB = wprojT + (size_t)(n0 + wave * 32 + r8) * CC + js * 8;
    u16* lA = As + wave * 32 * 64;
    u16* lB = Bs + wave * 32 * 64;

    for (int kt = 0; kt < 8; ++kt) {
        int k0 = kt * 64;
#pragma unroll
        for (int t = 0; t < 4; ++t) {
            dma16(gA + (size_t)t * 8 * CC + k0, lA + t * 8 * 64);
            dma16(gB + (size_t)t * 8 * CC + k0, lB + t * 8 * 64);
        }
        __syncthreads();
#pragma unroll
        for (int kk = 0; kk < 2; ++kk) {
            int ch = ((kk * 4 + quad) ^ sw) * 8;
            bf16x8 a[4], bb[4];
#pragma unroll
            for (int i = 0; i < 4; ++i) a[i] = *(const bf16x8*)&As[arow[i] + ch];
#pragma unroll
            for (int j = 0; j < 4; ++j) bb[j] = *(const bf16x8*)&Bs[brow[j] + ch];
#pragma unroll
            for (int i = 0; i < 4; ++i)
#pragma unroll
                for (int j = 0; j < 4; ++j)
                    acc[i][j] = __builtin_amdgcn_mfma_f32_16x16x32_bf16(a[i], bb[j], acc[i][j], 0, 0, 0);
        }
        __syncthreads();
    }
#pragma unroll
    for (int i = 0; i < 4; ++i)
#pragma unroll
        for (int j = 0; j < 4; ++j) {
            int col = n0 + nwl + j * 16 + l15;
            float bp = b_proj[col];
#pragma unroll
            for (int r = 0; r < 4; ++r) {
                int row = m0 + mwl + i * 16 + quad * 4 + r;
                out[(size_t)row * CC + col] = acc[i][j][r] + bp;
            }
        }
}

// ---------------- fused per-(b,nb,h) attention ----------------
__global__ __launch_bounds__(256) void attn_kernel(const u16* __restrict__ qkv,
                                                   const u16* __restrict__ sbias2,
                                                   const u16* __restrict__ gate2,
                                                   const float* __restrict__ gbl,
                                                   u16* __restrict__ xmid) {
    __shared__ u16 VT[64 * 72], Ps[64 * 72];
    __shared__ float gl[64], vbl[64];
    int tid = threadIdx.x;
    int bid = blockIdx.x;
    int h = bid & 7, nb = (bid >> 3) & 511, b = bid >> 12;
    int lane = tid & 63, l15 = lane & 15, quad = lane >> 4, wave = tid >> 6;
    int m0 = wave * 16;
    size_t blockrow = (size_t)(b * NTOK + nb * 64);
    const u16* qbase = qkv + blockrow * 1536 + h * 64;

    {
        int key = tid & 63, d0 = (tid >> 6) * 16;
        const uint4* vsrc = (const uint4*)(qbase + (size_t)key * 1536 + 1024 + d0);
        uint4 v0 = vsrc[0], v1 = vsrc[1];
        u16 tmp[16];
        *(uint4*)tmp = v0;
        *(uint4*)(tmp + 8) = v1;
#pragma unroll
        for (int j = 0; j < 16; ++j) VT[(d0 + j) * 72 + key] = tmp[j];
    }
    if (tid < 64) gl[tid] = gbl[(blockrow + tid) * 8 + h];
    __syncthreads();

    if (tid < 64) {
        float s = 0.f;
#pragma unroll 8
        for (int k = 0; k < 64; ++k) s += bf2f(VT[tid * 72 + k]);
        vbl[tid] = s * 0.015625f;
    }

    f32x4 sc[4];
#pragma unroll
    for (int t = 0; t < 4; ++t) sc[t] = (f32x4){0.f, 0.f, 0.f, 0.f};
#pragma unroll
    for (int kk = 0; kk < 2; ++kk) {
        bf16x8 a = bc8(*(const uint4*)(qbase + (size_t)(m0 + l15) * 1536 + kk * 32 + quad * 8));
#pragma unroll
        for (int t = 0; t < 4; ++t) {
            bf16x8 bb = bc8(*(const uint4*)(qbase + (size_t)(t * 16 + l15) * 1536 + 512 + kk * 32 + quad * 8));
            sc[t] = __builtin_amdgcn_mfma_f32_16x16x32_bf16(a, bb, sc[t], 0, 0, 0);
        }
    }
    {
        const u16* sb2 = sbias2 + (size_t)nb * 4096;
        const u16* gp2 = gate2 + ((size_t)nb * 8 + h) * 4096;
#pragma unroll
        for (int r = 0; r < 4; ++r) {
            int q = m0 + quad * 4 + r;
            ushort4 sv = *(const ushort4*)(sb2 + (q * 16 + l15) * 4);
            float bias_t[4] = {bf2f(sv.x), bf2f(sv.y), bf2f(sv.z), bf2f(sv.w)};
            float mx = -3e38f;
#pragma unroll
            for (int t = 0; t < 4; ++t) {
                float v = sc[t][r] * 0.125f + bias_t[t];
                sc[t][r] = v;
                mx = fmaxf(mx, v);
            }
            mx = fmaxf(mx, __shfl_xor(mx, 1));
            mx = fmaxf(mx, __shfl_xor(mx, 2));
            mx = fmaxf(mx, __shfl_xor(mx, 4));
            mx = fmaxf(mx, __shfl_xor(mx, 8));
            float sum = 0.f;
#pragma unroll
            for (int t = 0; t < 4; ++t) {
                float p = __expf(sc[t][r] - mx);
                sc[t][r] = p;
                sum += p;
            }
            sum += __shfl_xor(sum, 1);
            sum += __shfl_xor(sum, 2);
            sum += __shfl_xor(sum, 4);
            sum += __shfl_xor(sum, 8);
            float inv = 1.f / sum;
            ushort4 gv = *(const ushort4*)(gp2 + (q * 16 + l15) * 4);
            float gate_t[4] = {bf2f(gv.x), bf2f(gv.y), bf2f(gv.z), bf2f(gv.w)};
#pragma unroll
            for (int t = 0; t < 4; ++t) {
                float comb = sc[t][r] * inv + gate_t[t];
                Ps[q * 72 + t * 16 + l15] = f2bf(comb);
            }
        }
    }
    __syncthreads();

    f32x4 o[4];
#pragma unroll
    for (int t = 0; t < 4; ++t) o[t] = (f32x4){0.f, 0.f, 0.f, 0.f};
#pragma unroll
    for (int kk = 0; kk < 2; ++kk) {
        bf16x8 a = *(const bf16x8*)&Ps[(m0 + l15) * 72 + kk * 32 + quad * 8];
#pragma unroll
        for (int t = 0; t < 4; ++t) {
            bf16x8 bb = *(const bf16x8*)&VT[(t * 16 + l15) * 72 + kk * 32 + quad * 8];
            o[t] = __builtin_amdgcn_mfma_f32_16x16x32_bf16(a, bb, o[t], 0, 0, 0);
        }
    }
#pragma unroll
    for (int t = 0; t < 4; ++t) {
#pragma unroll
        for (int r = 0; r < 4; ++r) {
            int q = m0 + quad * 4 + r, d = t * 16 + l15;
            float v = o[t][r] + gl[q] * vbl[d];
            xmid[(blockrow + q) * CC + h * 64 + d] = f2bf(v);
        }
    }
}

extern "C" void kernel_launch(void* const* d_in, const int* in_sizes, int n_in,
                              void* d_out, int out_size, void* d_ws, size_t ws_size,
                              hipStream_t stream) {
    const float* x = (const float*)d_in[0];
    const int* attn_mask = (const int*)d_in[1];
    const float* edge = (const float*)d_in[2];
    const float* w_qkv = (const float*)d_in[3];
    const float* b_qkv = (const float*)d_in[4];
    const float* w_proj = (const float*)d_in[5];
    const float* b_proj = (const float*)d_in[6];
    const float* w_eg1 = (const float*)d_in[7];
    const float* b_eg1 = (const float*)d_in[8];
    const float* w_eg2 = (const float*)d_in[9];
    const float* b_eg2 = (const float*)d_in[10];
    const float* w_blk = (const float*)d_in[11];
    const float* b_blk = (const float*)d_in[12];
    float* out = (float*)d_out;

    char* ws = (char*)d_ws;
    u16* xbf = (u16*)ws;                            // 67108864 bytes
    u16* xmid = (u16*)ws;                           // alias (xbf consumed before attn writes)
    u16* qkv = (u16*)(ws + 67108864);               // 201326592
    u16* gate2 = (u16*)(ws + 268435456);            // 33554432
    u16* sbias2 = (u16*)(ws + 301989888);           // 4194304
    u16* wqkvT = (u16*)(ws + 306184192);            // 1572864
    u16* wprojT = (u16*)(ws + 307757056);           // 524288
    float* gbl = (float*)(ws + 308281344);          // 2097152

    convert_gblock_kernel<<<16384, 256, 0, stream>>>(x, xbf, w_blk, b_blk, gbl);
    transpose_bf16_kernel<<<dim3(48, 16), 256, 0, stream>>>(w_qkv, wqkvT, 512, 1536);
    transpose_bf16_kernel<<<dim3(16, 16), 256, 0, stream>>>(w_proj, wprojT, 512, 512);
    gate_sbias_kernel<<<512, 256, 0, stream>>>(attn_mask, edge, w_eg1, b_eg1, w_eg2, b_eg2,
                                               gate2, sbias2);
    qkv_gemm_kernel<<<dim3(12, 512), 256, 0, stream>>>(xbf, wqkvT, b_qkv, qkv);
    attn_kernel<<<8192, 256, 0, stream>>>(qkv, sbias2, gate2, gbl, xmid);
    outproj_kernel<<<dim3(4, 512), 256, 0, stream>>>(xmid, wprojT, b_proj, out);
}